// Round 1
// baseline (865.694 us; speedup 1.0000x reference)
//
#include <hip/hip_runtime.h>
#include <hip/hip_bf16.h>
#include <cstdint>

typedef __bf16 bf16x8 __attribute__((ext_vector_type(8)));
typedef float  f32x4  __attribute__((ext_vector_type(4)));

__device__ __forceinline__ unsigned short f2bf_bits(float f) {
    unsigned int u = __builtin_bit_cast(unsigned int, f);
    u = u + 0x7FFFu + ((u >> 16) & 1u);
    return (unsigned short)(u >> 16);
}

// ---------------------------------------------------------------------------
// Pack weights into MFMA B-fragment order, bf16.
// Wp layout: [nt][kb][c][j]  element = W[kb*8+j][nt*16+c]
// wp_edge: 384x256 -> nt=16, kb=48.   wp_cat: 128x160 -> nt=10, kb=16.
// cat columns: [0,16)=W_rbf_h [16,32)=W_rbf_out [32,48)=W_rbf_tint [48,160)=W_cbf flat
// ---------------------------------------------------------------------------
__global__ __launch_bounds__(256) void pack_weights_kernel(
    const float* __restrict__ W_edge,
    const float* __restrict__ W_rbf_h,
    const float* __restrict__ W_rbf_out,
    const float* __restrict__ W_rbf_tint,
    const float* __restrict__ W_cbf,
    unsigned short* __restrict__ wp_edge,
    unsigned short* __restrict__ wp_cat)
{
    int i = blockIdx.x * 256 + threadIdx.x;
    if (i < 98304) {
        int j = i & 7, c = (i >> 3) & 15, t2 = i >> 7;
        int kb = t2 % 48, nt = t2 / 48;
        int r = kb * 8 + j, col = nt * 16 + c;
        wp_edge[i] = f2bf_bits(W_edge[r * 256 + col]);
    }
    int i2 = i - 98304;
    if (i2 >= 0 && i2 < 20480) {
        int j = i2 & 7, c = (i2 >> 3) & 15, t2 = i2 >> 7;
        int kb = t2 & 15, nt = t2 >> 4;
        int r = kb * 8 + j, col = nt * 16 + c;
        float v;
        if      (col < 16)  v = W_rbf_h  [r * 16 + col];
        else if (col < 32)  v = W_rbf_out[r * 16 + (col - 16)];
        else if (col < 48)  v = W_rbf_tint[r * 16 + (col - 32)];
        else                v = W_cbf   [r * 112 + (col - 48)];
        wp_cat[i2] = f2bf_bits(v);
    }
}

// ---------------------------------------------------------------------------
// Kernel 1: rad_main (on the fly) @ [W_rbf_h | W_rbf_out | W_rbf_tint | W_cbf]
// M=NE, N=160, K=128, bf16 MFMA. One wave = 16 edges, block = 4 waves.
// ---------------------------------------------------------------------------
__global__ __launch_bounds__(256) void rad_small_kernel(
    const float* __restrict__ D_st,
    const unsigned short* __restrict__ wp_cat,
    float* __restrict__ out, int NE)
{
    const int lane  = threadIdx.x & 63;
    const int wave  = threadIdx.x >> 6;
    const int col16 = lane & 15;
    const int ksub  = lane >> 4;
    const int e0    = blockIdx.x * 64 + wave * 16;

    const int er = e0 + col16;
    const int es = er < NE ? er : NE - 1;
    const float d = D_st[es] * (1.0f / 12.0f);
    float d2 = d * d;
    float d5 = d2 * d2 * d;
    float env = 1.0f + d5 * (-21.0f + d * (35.0f + d * -15.0f));
    env = (d < 1.0f) ? env : 0.0f;

    const bf16x8* __restrict__ bp = (const bf16x8*)wp_cat;

    f32x4 acc[10];
    #pragma unroll
    for (int i = 0; i < 10; ++i) acc[i] = (f32x4){0.f, 0.f, 0.f, 0.f};

    #pragma unroll
    for (int kstep = 0; kstep < 4; ++kstep) {
        const int kb = kstep * 4 + ksub;          // 0..15
        const int r0 = kb * 8;
        bf16x8 af;
        #pragma unroll
        for (int j = 0; j < 8; ++j) {
            float t = d - (float)(r0 + j) * (1.0f / 127.0f);
            af[j] = (__bf16)(env * __expf(-8064.5f * t * t));
        }
        #pragma unroll
        for (int nt = 0; nt < 10; ++nt) {
            bf16x8 bf = bp[(nt * 16 + kb) * 16 + col16];
            acc[nt] = __builtin_amdgcn_mfma_f32_16x16x32_bf16(af, bf, acc[nt], 0, 0, 0);
        }
    }

    const size_t O_atom = (size_t)NE * 256;
    const size_t O_out  = O_atom + (size_t)NE * 16;
    const size_t O_e2e  = O_out  + (size_t)NE * 16;
    const size_t O_w1   = O_e2e  + (size_t)NE * 16;

    #pragma unroll
    for (int nt = 0; nt < 10; ++nt) {
        #pragma unroll
        for (int r = 0; r < 4; ++r) {
            const int eo = e0 + ksub * 4 + r;
            if (eo < NE) {
                const int c = nt * 16 + col16;
                const float v = acc[nt][r];
                if      (c < 16)  out[O_atom + (size_t)eo * 16  + c]        = v;
                else if (c < 32)  out[O_out  + (size_t)eo * 16  + (c - 16)] = v;
                else if (c < 48)  out[O_e2e  + (size_t)eo * 16  + (c - 32)] = v;
                else              out[O_w1   + (size_t)eo * 112 + (c - 48)] = v;
            }
        }
    }
}

// ---------------------------------------------------------------------------
// Kernel 2: m = ScaledSiLU([h_s | h_t | rad] @ W_edge)
// M=NE, N=256, K=384, bf16 MFMA. One wave = 16 edges, block = 4 waves.
// A built in-register: k<128 -> h[idx_s], k<256 -> h[idx_t], else rad on the fly.
// ---------------------------------------------------------------------------
__global__ __launch_bounds__(256) void edge_gemm_kernel(
    const float* __restrict__ h,
    const float* __restrict__ D_st,
    const int* __restrict__ idx_s,
    const int* __restrict__ idx_t,
    const unsigned short* __restrict__ wp_edge,
    float* __restrict__ out_m, int NE)
{
    const int lane  = threadIdx.x & 63;
    const int wave  = threadIdx.x >> 6;
    const int col16 = lane & 15;
    const int ksub  = lane >> 4;
    const int e0    = blockIdx.x * 64 + wave * 16;

    const int er = e0 + col16;
    const int es = er < NE ? er : NE - 1;
    const int is = idx_s[es];
    const int it = idx_t[es];
    const float d = D_st[es] * (1.0f / 12.0f);
    float d2 = d * d;
    float d5 = d2 * d2 * d;
    float env = 1.0f + d5 * (-21.0f + d * (35.0f + d * -15.0f));
    env = (d < 1.0f) ? env : 0.0f;

    const bf16x8* __restrict__ bp = (const bf16x8*)wp_edge;

    f32x4 acc[16];
    #pragma unroll
    for (int i = 0; i < 16; ++i) acc[i] = (f32x4){0.f, 0.f, 0.f, 0.f};

    #pragma unroll
    for (int kstep = 0; kstep < 12; ++kstep) {
        const int kb = kstep * 4 + ksub;          // 0..47
        bf16x8 af;
        if (kstep < 8) {
            const int row = (kstep < 4) ? is : it;
            const float* src = h + (size_t)row * 128 + ((kb * 8) & 127);
            f32x4 x0 = *(const f32x4*)src;
            f32x4 x1 = *(const f32x4*)(src + 4);
            #pragma unroll
            for (int j = 0; j < 4; ++j) { af[j] = (__bf16)x0[j]; af[4 + j] = (__bf16)x1[j]; }
        } else {
            const int r0 = kb * 8 - 256;
            #pragma unroll
            for (int j = 0; j < 8; ++j) {
                float t = d - (float)(r0 + j) * (1.0f / 127.0f);
                af[j] = (__bf16)(env * __expf(-8064.5f * t * t));
            }
        }
        #pragma unroll
        for (int nt = 0; nt < 16; ++nt) {
            bf16x8 bf = bp[(nt * 48 + kb) * 16 + col16];
            acc[nt] = __builtin_amdgcn_mfma_f32_16x16x32_bf16(af, bf, acc[nt], 0, 0, 0);
        }
    }

    #pragma unroll
    for (int nt = 0; nt < 16; ++nt) {
        #pragma unroll
        for (int r = 0; r < 4; ++r) {
            const int eo = e0 + ksub * 4 + r;
            if (eo < NE) {
                float z  = acc[nt][r];
                float sg = 1.0f / (1.0f + __expf(-z));
                out_m[(size_t)eo * 256 + nt * 16 + col16] = z * sg * (1.0f / 0.6f);
            }
        }
    }
}

// ---------------------------------------------------------------------------
// Kernel 3: triplet circular basis -> scatter into sph.
// ---------------------------------------------------------------------------
__global__ __launch_bounds__(256) void triplet_kernel(
    const float* __restrict__ V_st,
    const int* __restrict__ id3_ba,
    const int* __restrict__ id3_ca,
    const int* __restrict__ out_agg,
    float* __restrict__ out_sph,
    int NT, int Kmax)
{
    int t = blockIdx.x * 256 + threadIdx.x;
    if (t >= NT) return;
    int ca = id3_ca[t];
    int ba = id3_ba[t];
    int ag = out_agg[t];
    const float* va = V_st + (size_t)ca * 3;
    const float* vb = V_st + (size_t)ba * 3;
    float x = va[0] * vb[0] + va[1] * vb[1] + va[2] * vb[2];
    x = fminf(1.0f, fmaxf(-1.0f, x));
    float P0 = 1.0f;
    float P1 = x;
    float P2 = (3.0f  * x * P1 - 1.0f * P0) / 2.0f;
    float P3 = (5.0f  * x * P2 - 2.0f * P1) / 3.0f;
    float P4 = (7.0f  * x * P3 - 3.0f * P2) / 4.0f;
    float P5 = (9.0f  * x * P4 - 4.0f * P3) / 5.0f;
    float P6 = (11.0f * x * P5 - 5.0f * P4) / 6.0f;
    float* o = out_sph + ((size_t)ca * Kmax + ag) * 7;
    o[0] = 0.28209479f * P0;
    o[1] = 0.48860251f * P1;
    o[2] = 0.63078313f * P2;
    o[3] = 0.74635267f * P3;
    o[4] = 0.84628438f * P4;
    o[5] = 0.93560258f * P5;
    o[6] = 1.01710723f * P6;
}

extern "C" void kernel_launch(void* const* d_in, const int* in_sizes, int n_in,
                              void* d_out, int out_size, void* d_ws, size_t ws_size,
                              hipStream_t stream) {
    const float* h        = (const float*)d_in[0];
    const float* D_st     = (const float*)d_in[1];
    const float* V_st     = (const float*)d_in[2];
    const int*   idx_s    = (const int*)d_in[3];
    const int*   idx_t    = (const int*)d_in[4];
    const int*   id3_ba   = (const int*)d_in[5];
    const int*   id3_ca   = (const int*)d_in[6];
    const int*   out_agg  = (const int*)d_in[7];
    // d_in[8] = Kmax scalar (recovered from out_size instead)
    const float* W_edge   = (const float*)d_in[9];
    const float* W_rbf_h  = (const float*)d_in[10];
    const float* W_rbf_o  = (const float*)d_in[11];
    const float* W_rbf_t  = (const float*)d_in[12];
    const float* W_cbf    = (const float*)d_in[13];

    const int NE = in_sizes[1];
    const int NT = in_sizes[5];
    float* out = (float*)d_out;

    // output layout: m | atom_update | output | e2e_rad | rad_W1 | sph
    const size_t O_sph     = (size_t)NE * 416;   // 256 + 16*3 + 112
    const size_t sph_elems = (size_t)out_size - O_sph;
    const int    Kmax      = (int)(sph_elems / ((size_t)NE * 7));

    unsigned short* wp_edge = (unsigned short*)d_ws;   // 98304 bf16
    unsigned short* wp_cat  = wp_edge + 98304;         // 20480 bf16

    pack_weights_kernel<<<464, 256, 0, stream>>>(W_edge, W_rbf_h, W_rbf_o, W_rbf_t,
                                                 W_cbf, wp_edge, wp_cat);

    const int nblk = (NE + 63) / 64;
    rad_small_kernel<<<nblk, 256, 0, stream>>>(D_st, wp_cat, out, NE);
    edge_gemm_kernel<<<nblk, 256, 0, stream>>>(h, D_st, idx_s, idx_t, wp_edge, out, NE);

    hipMemsetAsync(out + O_sph, 0, sph_elems * sizeof(float), stream);
    triplet_kernel<<<(NT + 255) / 256, 256, 0, stream>>>(V_st, id3_ba, id3_ca, out_agg,
                                                         out + O_sph, NT, Kmax);
}

// Round 2
// 722.419 us; speedup vs baseline: 1.1983x; 1.1983x over previous
//
#include <hip/hip_runtime.h>
#include <hip/hip_bf16.h>
#include <cstdint>

typedef __bf16 bf16x8 __attribute__((ext_vector_type(8)));
typedef float  f32x4  __attribute__((ext_vector_type(4)));

__device__ __forceinline__ unsigned short f2bf_bits(float f) {
    unsigned int u = __builtin_bit_cast(unsigned int, f);
    u = u + 0x7FFFu + ((u >> 16) & 1u);
    return (unsigned short)(u >> 16);
}

// ---------------------------------------------------------------------------
// Pack weights into MFMA B-fragment order, bf16.
// Wp layout: [nt][kb][c][j]  element = W[kb*8+j][nt*16+c]
// wp_edge: 384x256 -> nt=16, kb=48.   wp_cat: 128x160 -> nt=10, kb=16.
// cat columns: [0,16)=W_rbf_h [16,32)=W_rbf_out [32,48)=W_rbf_tint [48,160)=W_cbf flat
// ---------------------------------------------------------------------------
__global__ __launch_bounds__(256) void pack_weights_kernel(
    const float* __restrict__ W_edge,
    const float* __restrict__ W_rbf_h,
    const float* __restrict__ W_rbf_out,
    const float* __restrict__ W_rbf_tint,
    const float* __restrict__ W_cbf,
    unsigned short* __restrict__ wp_edge,
    unsigned short* __restrict__ wp_cat)
{
    int i = blockIdx.x * 256 + threadIdx.x;
    if (i < 98304) {
        int j = i & 7, c = (i >> 3) & 15, t2 = i >> 7;
        int kb = t2 % 48, nt = t2 / 48;
        int r = kb * 8 + j, col = nt * 16 + c;
        wp_edge[i] = f2bf_bits(W_edge[r * 256 + col]);
    }
    int i2 = i - 98304;
    if (i2 >= 0 && i2 < 20480) {
        int j = i2 & 7, c = (i2 >> 3) & 15, t2 = i2 >> 7;
        int kb = t2 & 15, nt = t2 >> 4;
        int r = kb * 8 + j, col = nt * 16 + c;
        float v;
        if      (col < 16)  v = W_rbf_h  [r * 16 + col];
        else if (col < 32)  v = W_rbf_out[r * 16 + (col - 16)];
        else if (col < 48)  v = W_rbf_tint[r * 16 + (col - 32)];
        else                v = W_cbf   [r * 112 + (col - 48)];
        wp_cat[i2] = f2bf_bits(v);
    }
}

// ---------------------------------------------------------------------------
// Fused kernel: per block of 64 edges,
//   stage A = [h_s | h_t | rbf] (64 x 384 bf16) in LDS (padded stride),
//   K-loop1: m = ScaledSiLU(A @ W_edge)       (waves N-split, 4 nt each)
//   K-loop2: rbf rows of A @ W_cat -> atom_update/output/e2e_rad/rad_W1
// ---------------------------------------------------------------------------
#define LDA 392   // bf16 elements per A_lds row: 384 + 8 pad (784B stride)

__global__ __launch_bounds__(256, 3) void fused_gemm_kernel(
    const float* __restrict__ h,
    const float* __restrict__ D_st,
    const int* __restrict__ idx_s,
    const int* __restrict__ idx_t,
    const unsigned short* __restrict__ wp_edge,
    const unsigned short* __restrict__ wp_cat,
    float* __restrict__ out, int NE)
{
    __shared__ __align__(16) unsigned short A_lds[64 * LDA];
    const int tid = threadIdx.x;
    const int e0  = blockIdx.x * 64;

    // ---- staging: 256 threads, thread = (edge e, segment seg) ----
    {
        const int e   = tid & 63;
        const int seg = tid >> 6;                 // 0..3
        const int eg  = e0 + e;
        const int ec  = eg < NE ? eg : NE - 1;
        const int hrow = (seg < 2) ? idx_s[ec] : idx_t[ec];
        const float* hp = h + (size_t)hrow * 128 + (seg & 1) * 64;
        unsigned short* arow = A_lds + e * LDA;
        #pragma unroll
        for (int q = 0; q < 8; ++q) {
            f32x4 x0 = *(const f32x4*)(hp + q * 8);
            f32x4 x1 = *(const f32x4*)(hp + q * 8 + 4);
            bf16x8 v;
            #pragma unroll
            for (int j = 0; j < 4; ++j) { v[j] = (__bf16)x0[j]; v[4 + j] = (__bf16)x1[j]; }
            *(bf16x8*)(arow + (seg * 8 + q) * 8) = v;
        }
        // rbf chunk: this thread covers radial indices [seg*32, seg*32+32)
        const float d = D_st[ec] * (1.0f / 12.0f);
        float d2 = d * d;
        float d5 = d2 * d2 * d;
        float env = 1.0f + d5 * (-21.0f + d * (35.0f + d * -15.0f));
        env = (d < 1.0f) ? env : 0.0f;
        #pragma unroll
        for (int q = 0; q < 4; ++q) {
            bf16x8 v;
            #pragma unroll
            for (int j = 0; j < 8; ++j) {
                int ridx = seg * 32 + q * 8 + j;
                float t = d - (float)ridx * (1.0f / 127.0f);
                v[j] = (__bf16)(env * __expf(-8064.5f * t * t));
            }
            *(bf16x8*)(arow + (32 + seg * 4 + q) * 8) = v;
        }
    }
    __syncthreads();

    const int lane  = tid & 63;
    const int w     = tid >> 6;
    const int col16 = lane & 15;
    const int ksub  = lane >> 4;
    const bf16x8* __restrict__ bpe = (const bf16x8*)wp_edge;
    const bf16x8* __restrict__ bpc = (const bf16x8*)wp_cat;

    // ---- K-loop 1: m ----
    f32x4 acc1[4][4];
    #pragma unroll
    for (int m = 0; m < 4; ++m)
        #pragma unroll
        for (int n = 0; n < 4; ++n) acc1[m][n] = (f32x4){0.f, 0.f, 0.f, 0.f};

    #pragma unroll
    for (int kstep = 0; kstep < 12; ++kstep) {
        const int kb = kstep * 4 + ksub;          // 0..47
        bf16x8 af[4];
        #pragma unroll
        for (int m = 0; m < 4; ++m)
            af[m] = *(const bf16x8*)(A_lds + (m * 16 + col16) * LDA + kb * 8);
        #pragma unroll
        for (int n = 0; n < 4; ++n) {
            bf16x8 bf = bpe[((w * 4 + n) * 48 + kb) * 16 + col16];
            #pragma unroll
            for (int m = 0; m < 4; ++m)
                acc1[m][n] = __builtin_amdgcn_mfma_f32_16x16x32_bf16(af[m], bf, acc1[m][n], 0, 0, 0);
        }
    }
    #pragma unroll
    for (int m = 0; m < 4; ++m) {
        #pragma unroll
        for (int n = 0; n < 4; ++n) {
            #pragma unroll
            for (int r = 0; r < 4; ++r) {
                const int eo = e0 + m * 16 + ksub * 4 + r;
                if (eo < NE) {
                    float z  = acc1[m][n][r];
                    float sg = 1.0f / (1.0f + __expf(-z));
                    out[(size_t)eo * 256 + (w * 4 + n) * 16 + col16] = z * sg * (1.0f / 0.6f);
                }
            }
        }
    }

    // ---- K-loop 2: small outputs from rbf rows (A chunks 32..47) ----
    const int nt0 = (w < 2) ? w * 3 : 6 + (w - 2) * 2;   // 0,3,6,8
    const int cnt = (w < 2) ? 3 : 2;
    f32x4 acc2[3][4];
    #pragma unroll
    for (int n = 0; n < 3; ++n)
        #pragma unroll
        for (int m = 0; m < 4; ++m) acc2[n][m] = (f32x4){0.f, 0.f, 0.f, 0.f};

    #pragma unroll
    for (int kstep = 0; kstep < 4; ++kstep) {
        const int kb2 = kstep * 4 + ksub;         // 0..15
        bf16x8 af[4];
        #pragma unroll
        for (int m = 0; m < 4; ++m)
            af[m] = *(const bf16x8*)(A_lds + (m * 16 + col16) * LDA + (32 + kb2) * 8);
        #pragma unroll
        for (int n = 0; n < 3; ++n) {
            if (n < cnt) {
                bf16x8 bf = bpc[((nt0 + n) * 16 + kb2) * 16 + col16];
                #pragma unroll
                for (int m = 0; m < 4; ++m)
                    acc2[n][m] = __builtin_amdgcn_mfma_f32_16x16x32_bf16(af[m], bf, acc2[n][m], 0, 0, 0);
            }
        }
    }

    const size_t O_atom = (size_t)NE * 256;
    const size_t O_out  = O_atom + (size_t)NE * 16;
    const size_t O_e2e  = O_out  + (size_t)NE * 16;
    const size_t O_w1   = O_e2e  + (size_t)NE * 16;

    #pragma unroll
    for (int n = 0; n < 3; ++n) {
        if (n < cnt) {
            const int nt = nt0 + n;
            size_t base; int stride;
            if      (nt == 0) { base = O_atom; stride = 16; }
            else if (nt == 1) { base = O_out;  stride = 16; }
            else if (nt == 2) { base = O_e2e;  stride = 16; }
            else              { base = O_w1 + (size_t)(nt - 3) * 16; stride = 112; }
            #pragma unroll
            for (int m = 0; m < 4; ++m) {
                #pragma unroll
                for (int r = 0; r < 4; ++r) {
                    const int eo = e0 + m * 16 + ksub * 4 + r;
                    if (eo < NE)
                        out[base + (size_t)eo * stride + col16] = acc2[n][m][r];
                }
            }
        }
    }
}

// ---------------------------------------------------------------------------
// Triplet circular basis -> sph. (ca,ag) = (t/K, t%K) is a bijection onto
// [NE]x[K] (id3_ca=repeat, out_agg=tile), so every sph element is written:
// no memset needed.
// ---------------------------------------------------------------------------
__global__ __launch_bounds__(256) void triplet_kernel(
    const float* __restrict__ V_st,
    const int* __restrict__ id3_ba,
    const int* __restrict__ id3_ca,
    const int* __restrict__ out_agg,
    float* __restrict__ out_sph,
    int NT, int Kmax)
{
    int t = blockIdx.x * 256 + threadIdx.x;
    if (t >= NT) return;
    int ca = id3_ca[t];
    int ba = id3_ba[t];
    int ag = out_agg[t];
    const float* va = V_st + (size_t)ca * 3;
    const float* vb = V_st + (size_t)ba * 3;
    float x = va[0] * vb[0] + va[1] * vb[1] + va[2] * vb[2];
    x = fminf(1.0f, fmaxf(-1.0f, x));
    float P0 = 1.0f;
    float P1 = x;
    float P2 = (3.0f  * x * P1 - 1.0f * P0) / 2.0f;
    float P3 = (5.0f  * x * P2 - 2.0f * P1) / 3.0f;
    float P4 = (7.0f  * x * P3 - 3.0f * P2) / 4.0f;
    float P5 = (9.0f  * x * P4 - 4.0f * P3) / 5.0f;
    float P6 = (11.0f * x * P5 - 5.0f * P4) / 6.0f;
    float* o = out_sph + ((size_t)ca * Kmax + ag) * 7;
    o[0] = 0.28209479f * P0;
    o[1] = 0.48860251f * P1;
    o[2] = 0.63078313f * P2;
    o[3] = 0.74635267f * P3;
    o[4] = 0.84628438f * P4;
    o[5] = 0.93560258f * P5;
    o[6] = 1.01710723f * P6;
}

extern "C" void kernel_launch(void* const* d_in, const int* in_sizes, int n_in,
                              void* d_out, int out_size, void* d_ws, size_t ws_size,
                              hipStream_t stream) {
    const float* h        = (const float*)d_in[0];
    const float* D_st     = (const float*)d_in[1];
    const float* V_st     = (const float*)d_in[2];
    const int*   idx_s    = (const int*)d_in[3];
    const int*   idx_t    = (const int*)d_in[4];
    const int*   id3_ba   = (const int*)d_in[5];
    const int*   id3_ca   = (const int*)d_in[6];
    const int*   out_agg  = (const int*)d_in[7];
    // d_in[8] = Kmax scalar (recovered from out_size instead)
    const float* W_edge   = (const float*)d_in[9];
    const float* W_rbf_h  = (const float*)d_in[10];
    const float* W_rbf_o  = (const float*)d_in[11];
    const float* W_rbf_t  = (const float*)d_in[12];
    const float* W_cbf    = (const float*)d_in[13];

    const int NE = in_sizes[1];
    const int NT = in_sizes[5];
    float* out = (float*)d_out;

    // output layout: m | atom_update | output | e2e_rad | rad_W1 | sph
    const size_t O_sph     = (size_t)NE * 416;   // 256 + 16*3 + 112
    const size_t sph_elems = (size_t)out_size - O_sph;
    const int    Kmax      = (int)(sph_elems / ((size_t)NE * 7));

    unsigned short* wp_edge = (unsigned short*)d_ws;   // 98304 bf16
    unsigned short* wp_cat  = wp_edge + 98304;         // 20480 bf16

    pack_weights_kernel<<<464, 256, 0, stream>>>(W_edge, W_rbf_h, W_rbf_o, W_rbf_t,
                                                 W_cbf, wp_edge, wp_cat);

    const int nblk = (NE + 63) / 64;
    fused_gemm_kernel<<<nblk, 256, 0, stream>>>(h, D_st, idx_s, idx_t,
                                                wp_edge, wp_cat, out, NE);

    triplet_kernel<<<(NT + 255) / 256, 256, 0, stream>>>(V_st, id3_ba, id3_ca, out_agg,
                                                         out + O_sph, NT, Kmax);
}